// Round 12
// baseline (168.080 us; speedup 1.0000x reference)
//
#include <hip/hip_runtime.h>

// DP5 integrator, MI355X. fp32 in/out. Rank-128 recursion vs G'=-256·(W@U).
// R12: stage GEMM transposed (kU^T = G'^T @ P^T). A=G'^T uses the SAME ws frags
// (A-frag of G^T == B-frag of G). P-tile: 16 rows = Ph(0-7)|Pl(8-15), read as
// B-frags: 4 ds_read_b128/wave/stage (vs 8), 2 b64 writes, 8 MFMA (2 chains),
// combine via shfl_xor(8). State row-layout: lane c16<8 owns batch-row c16.
// Projections R11-verbatim + one-time bounce; epilogue fill direct, MFMA loop
// R11-verbatim. Prep unchanged (R11-validated).

typedef _Float16 v8h __attribute__((ext_vector_type(8)));
typedef _Float16 v4h __attribute__((ext_vector_type(4)));
typedef float v4f __attribute__((ext_vector_type(4)));
typedef unsigned short u16;
typedef unsigned int u32;

#define MFMAH __builtin_amdgcn_mfma_f32_16x16x32_f16
#define INV2048 4.8828125e-4f
#define INV256  0.00390625f

struct Tab {
  double a[7][7]; double b[7]; double A[7]; double XC[7][7]; double XF[7]; double cxc[7];
};
static constexpr Tab make_tab() {
  Tab t{};
  t.a[2][1]=1.0/5;
  t.a[3][1]=3.0/40;       t.a[3][2]=9.0/40;
  t.a[4][1]=44.0/45;      t.a[4][2]=-56.0/15;      t.a[4][3]=32.0/9;
  t.a[5][1]=19372.0/6561; t.a[5][2]=-25360.0/2187; t.a[5][3]=64448.0/6561; t.a[5][4]=-212.0/729;
  t.a[6][1]=9017.0/3168;  t.a[6][2]=-355.0/33;     t.a[6][3]=46732.0/5247; t.a[6][4]=49.0/176; t.a[6][5]=-5103.0/18656;
  t.b[1]=35.0/384; t.b[2]=0.0; t.b[3]=500.0/1113; t.b[4]=125.0/192; t.b[5]=-2187.0/6784; t.b[6]=11.0/84;
  for (int i=1;i<=6;++i){ double s=0; for(int j=1;j<i;++j) s+=t.a[i][j]; t.A[i]=s; }
  for (int i=1;i<=6;++i) for(int l=1;l<i;++l){ double s=0; for(int j=l+1;j<i;++j) s+=t.a[i][j]*t.a[j][l]; t.XC[i][l]=s; }
  for (int i=1;i<=6;++i){ double s=0; for(int j=1;j<i;++j) s+=t.a[i][j]*t.A[j]; t.XF[i]=s; }
  for (int j=1;j<=6;++j){ double s=0; for (int i=j+1;i<=6;++i) s+=t.b[i]*t.a[i][j]; t.cxc[j]=s; }
  return t;
}
static constexpr Tab TB = make_tab();

__device__ __forceinline__ int decode_steps(const void* p){
  int v = *(const int*)p;
  if (v >= 1 && v <= 512) return v;
  float f = *(const float*)p;
  if (f >= 1.f && f <= 512.f) return (int)f;
  return 8;
}
__device__ __forceinline__ void split2s(float x, _Float16& h, _Float16& l){
  h = (_Float16)x;
  l = (_Float16)((x - (float)h) * 2048.0f);
}

#define WS_GH 0
#define WS_GL 16384
#define WS_UH 32768
#define WS_UL 98304
#define WS_WH 163840
#define WS_WL 229376

__global__ __launch_bounds__(256) void k_prep1(const float* __restrict__ U,
                                               const float* __restrict__ W,
                                               _Float16* __restrict__ ws){
  const int b = blockIdx.x, tid = threadIdx.x;
  if (b < 256) {
    int idx = b*256 + tid;
    int r = idx >> 7, c = idx & 127;
    _Float16 h, l; split2s(U[idx]*256.f, h, l);
    int kb=r>>5, q=(r>>3)&3, j=r&7, nb=c>>4, cl=c&15;
    int slot = ((nb*16+kb)*64 + q*16+cl)*8 + j;
    ws[WS_UH + slot] = h; ws[WS_UL + slot] = l;
  } else {
    int idx = (b-256)*256 + tid;
    int r = idx >> 9, c = idx & 511;
    _Float16 h, l; split2s(W[idx]*256.f, h, l);
    int kb=r>>5, q=(r>>3)&3, j=r&7, nb=c>>4, cl=c&15;
    int slot = ((nb*4+kb)*64 + q*16+cl)*8 + j;
    ws[WS_WH + slot] = h; ws[WS_WL + slot] = l;
  }
}

__global__ __launch_bounds__(512) void k_prep2(const float* __restrict__ W,
                                               _Float16* __restrict__ ws){
  const int tid = threadIdx.x, b = blockIdx.x;
  const int ww = tid >> 6, lane = tid & 63, q = lane >> 4, c16 = lane & 15;
  const int nb = ww;
  const _Float16* uH = ws + WS_UH;
  const _Float16* uL = ws + WS_UL;
  v4f aH = {0,0,0,0}, aC0 = {0,0,0,0}, aC1 = {0,0,0,0};
  #pragma unroll
  for (int kb = 0; kb < 16; ++kb) {
    const float* wp = W + (b*16 + c16)*512 + kb*32 + q*8;
    float4 w0 = *(const float4*)wp;
    float4 w1 = *(const float4*)(wp + 4);
    float wv[8] = {w0.x,w0.y,w0.z,w0.w, w1.x,w1.y,w1.z,w1.w};
    v8h Ah, Al;
    #pragma unroll
    for (int j = 0; j < 8; ++j) {
      _Float16 h, l; split2s(-wv[j], h, l);
      Ah[j] = h; Al[j] = l;
    }
    int bo = ((nb*16 + kb)*64 + lane)*8;
    v8h Bh = *(const v8h*)(uH + bo);
    v8h Bl = *(const v8h*)(uL + bo);
    aH = MFMAH(Ah, Bh, aH, 0,0,0);
    if (kb & 1) {
      aC1 = MFMAH(Ah, Bl, aC1, 0,0,0);
      aC1 = MFMAH(Al, Bh, aC1, 0,0,0);
    } else {
      aC0 = MFMAH(Ah, Bl, aC0, 0,0,0);
      aC0 = MFMAH(Al, Bh, aC0, 0,0,0);
    }
  }
  #pragma unroll
  for (int r = 0; r < 4; ++r) {
    float g = aH[r] + (aC0[r] + aC1[r])*INV2048;
    _Float16 h, l; split2s(g, h, l);
    int m = b*16 + 4*q + r, n = nb*16 + c16;
    int slot = (((n>>4)*4 + (m>>5))*64 + ((m>>3)&3)*16 + (n&15))*8 + (m&7);
    ws[WS_GH + slot] = h; ws[WS_GL + slot] = l;
  }
}

#define ARENA 33280

__global__ __launch_bounds__(512,4) void dp5_main(
    const float* __restrict__ xg, const float* __restrict__ vg,
    const float* __restrict__ fg, const void* stepsp,
    const _Float16* __restrict__ ws, float* __restrict__ outg)
{
  __shared__ __align__(16) char arena[ARENA];
  _Float16* base = (_Float16*)arena;
  const _Float16* uH = ws + WS_UH;
  const _Float16* uL = ws + WS_UL;
  const _Float16* wH = ws + WS_WH;
  const _Float16* wL = ws + WS_WL;

  const int tid  = threadIdx.x;
  const int ww   = tid >> 6;
  const int lane = tid & 63;
  const int q    = lane >> 4;
  const int c16  = lane & 15;
  const int nb   = ww;
  const int kcol = nb*16 + c16;
  const int srcl = (q>>1)*16 + c16;
  const bool odd = (q & 1);
  const int rb   = blockIdx.x * 8;
  const int S    = decode_steps(stepsp);
  const float dt = 0.01f;

  v8h Gh[4], Gl[4];
  #pragma unroll
  for (int kb = 0; kb < 4; ++kb) {
    int off = ((nb*4 + kb)*64 + lane)*8;
    Gh[kb] = *(const v8h*)(ws + WS_GH + off);
    Gl[kb] = *(const v8h*)(ws + WS_GL + off);
  }

  // ---- projections (R11-verbatim) -> spread xU0/vU0/fU0 ----
  _Float16* tH = base;
  _Float16* tL = base + 8320;
  const int r16 = tid >> 5, c0 = (tid & 31)*16;
  float xU0[2], vU0[2], fU0[2];
  for (int pass = 0; pass < 2; ++pass) {
    if (pass == 0 || r16 < 8) {
      const float* sp;
      if (pass == 0) sp = (r16 < 8) ? (xg + (rb + r16)*512) : (vg + (rb + r16 - 8)*512);
      else           sp = fg + (rb + r16)*512;
      sp += c0;
      float4 g0 = *(const float4*)(sp);
      float4 g1 = *(const float4*)(sp + 4);
      float4 g2 = *(const float4*)(sp + 8);
      float4 g3 = *(const float4*)(sp + 12);
      float vals[16] = {g0.x,g0.y,g0.z,g0.w, g1.x,g1.y,g1.z,g1.w,
                        g2.x,g2.y,g2.z,g2.w, g3.x,g3.y,g3.z,g3.w};
      v8h vh0, vh1, vl0, vl1;
      #pragma unroll
      for (int j = 0; j < 8; ++j) {
        _Float16 h, l;
        split2s(vals[j], h, l);     vh0[j] = h; vl0[j] = l;
        split2s(vals[8+j], h, l);   vh1[j] = h; vl1[j] = l;
      }
      int o = r16*520 + c0;
      *(v8h*)(tH + o) = vh0; *(v8h*)(tH + o + 8) = vh1;
      *(v8h*)(tL + o) = vl0; *(v8h*)(tL + o + 8) = vl1;
    }
    __syncthreads();
    v4f aH0={0,0,0,0}, aH1={0,0,0,0}, aC0={0,0,0,0}, aC1={0,0,0,0};
    #pragma unroll
    for (int kb = 0; kb < 16; ++kb) {
      int ao = c16*520 + kb*32 + q*8;
      v8h Ah = *(const v8h*)(tH + ao);
      v8h Al = *(const v8h*)(tL + ao);
      int bo = ((nb*16 + kb)*64 + lane)*8;
      v8h Bh = *(const v8h*)(uH + bo);
      v8h Bl = *(const v8h*)(uL + bo);
      if (kb & 1) {
        aH1 = MFMAH(Ah, Bh, aH1, 0,0,0);
        aC1 = MFMAH(Ah, Bl, aC1, 0,0,0);
        aC1 = MFMAH(Al, Bh, aC1, 0,0,0);
      } else {
        aH0 = MFMAH(Ah, Bh, aH0, 0,0,0);
        aC0 = MFMAH(Ah, Bl, aC0, 0,0,0);
        aC0 = MFMAH(Al, Bh, aC0, 0,0,0);
      }
    }
    float at0 = ((aH0[0]+aH1[0]) + (aC0[0]+aC1[0])*INV2048)*INV256;
    float at1 = ((aH0[1]+aH1[1]) + (aC0[1]+aC1[1])*INV2048)*INV256;
    float at2 = ((aH0[2]+aH1[2]) + (aC0[2]+aC1[2])*INV2048)*INV256;
    float at3 = ((aH0[3]+aH1[3]) + (aC0[3]+aC1[3])*INV2048)*INV256;
    if (pass == 0) {
      float sx0=__shfl(at0,srcl,64), sx1=__shfl(at1,srcl,64);
      float sx2=__shfl(at2,srcl,64), sx3=__shfl(at3,srcl,64);
      xU0[0] = odd ? sx2 : sx0; xU0[1] = odd ? sx3 : sx1;
      int srclv = srcl + 32;
      float sv0=__shfl(at0,srclv,64), sv1=__shfl(at1,srclv,64);
      float sv2=__shfl(at2,srclv,64), sv3=__shfl(at3,srclv,64);
      vU0[0] = odd ? sv2 : sv0; vU0[1] = odd ? sv3 : sv1;
    } else {
      float sf0=__shfl(at0,srcl,64), sf1=__shfl(at1,srcl,64);
      float sf2=__shfl(at2,srcl,64), sf3=__shfl(at3,srcl,64);
      fU0[0] = odd ? sf2 : sf0; fU0[1] = odd ? sf3 : sf1;
    }
    __syncthreads();
  }

  // ---- bounce spread -> row-state ----
  float cxU4[4], cvU4[4], fU4[4];
  {
    float* T = (float*)arena;
    #pragma unroll
    for (int p2 = 0; p2 < 3; ++p2) {
      float i0 = (p2==0) ? xU0[0] : (p2==1) ? vU0[0] : fU0[0];
      float i1 = (p2==0) ? xU0[1] : (p2==1) ? vU0[1] : fU0[1];
      T[(2*q + 0)*132 + kcol] = i0;
      T[(2*q + 1)*132 + kcol] = i1;
      __syncthreads();
      if (c16 < 8) {
        float4 t4 = *(const float4*)(T + c16*132 + nb*16 + 4*q);
        float* o = (p2==0) ? cxU4 : (p2==1) ? cvU4 : fU4;
        o[0]=t4.x; o[1]=t4.y; o[2]=t4.z; o[3]=t4.w;
      }
      __syncthreads();
    }
  }

  // ---- rank-128 recursion (transposed stage GEMM) ----
  float kU6[6][4], Rr4[4], QXa4[4];
  #pragma unroll
  for (int j = 0; j < 4; ++j) {
    Rr4[j] = 0.f; QXa4[j] = 0.f;
    #pragma unroll
    for (int l = 0; l < 6; ++l) kU6[l][j] = 0.f;
  }

  int pb = 0;
  for (int s = 0; s < S; ++s) {
    float accX[4], accV[4], Pbs[4], Pxcs[4];
    #pragma unroll
    for (int j = 0; j < 4; ++j) { accX[j]=0.f; accV[j]=0.f; Pbs[j]=0.f; Pxcs[j]=0.f; }

    #pragma unroll
    for (int i = 1; i <= 6; ++i) {
      _Float16* bT = base + (pb ? 2176 : 0);
      const float dtA   = dt*(float)TB.A[i];
      const float dt2XF = dt*dt*(float)TB.XF[i];
      const float bi    = (float)TB.b[i];
      const float ci    = (float)TB.cxc[i];
      if (c16 < 8) {
        v4h hh, ll;
        #pragma unroll
        for (int j2 = 0; j2 < 4; ++j2) {
          float vv = cvU4[j2] + dtA*fU4[j2];
          float xx = cxU4[j2] + dtA*cvU4[j2] + dt2XF*fU4[j2];
          #pragma unroll
          for (int l = 1; l < i; ++l) {
            vv += (dt*(float)TB.a[i][l]) * kU6[l-1][j2];
            xx += (dt*dt*(float)TB.XC[i][l]) * kU6[l-1][j2];
          }
          float p = vv*xx;
          Pbs[j2] += bi*p; Pxcs[j2] += ci*p;
          _Float16 h, l2; split2s(p, h, l2);
          hh[j2] = h; ll[j2] = l2;
        }
        *(v4h*)(bT + c16*136 + nb*16 + 4*q)     = hh;
        *(v4h*)(bT + (8+c16)*136 + nb*16 + 4*q) = ll;
      }
      __syncthreads();
      v4f C1 = {0,0,0,0}, C2 = {0,0,0,0};
      #pragma unroll
      for (int kb = 0; kb < 4; ++kb) {
        v8h B = *(const v8h*)(bT + c16*136 + kb*32 + q*8);
        C1 = MFMAH(Gh[kb], B, C1, 0,0,0);
        C2 = MFMAH(Gl[kb], B, C2, 0,0,0);
      }
      #pragma unroll
      for (int r = 0; r < 4; ++r) {
        float lo = __shfl_xor(C1[r], 8, 64);
        float kv = (C1[r] + (lo + C2[r])*INV2048)*INV256;
        kU6[i-1][r] = kv;
        accX[r] += ci*kv; accV[r] += bi*kv;
      }
      pb ^= 1;
    }

    #pragma unroll
    for (int j = 0; j < 4; ++j) {
      float nx = cxU4[j] + dt*cvU4[j] + dt*dt*(accX[j] + 0.5f*fU4[j]);
      cvU4[j] += dt*(accV[j] + fU4[j]);
      cxU4[j]  = nx;
      QXa4[j] += Rr4[j] + Pxcs[j];
      Rr4[j]  += Pbs[j];
    }
  }

  // ---- epilogue ----
  __syncthreads();
  _Float16* RQh = base;
  _Float16* RQl = base + 2176;
  if (c16 < 8) {
    v4h h4, l4;
    #pragma unroll
    for (int j2 = 0; j2 < 4; ++j2) {
      _Float16 h, l; split2s(Rr4[j2], h, l);
      h4[j2] = h; l4[j2] = l;
    }
    *(v4h*)(RQh + c16*136 + nb*16 + 4*q) = h4;
    *(v4h*)(RQl + c16*136 + nb*16 + 4*q) = l4;
    #pragma unroll
    for (int j2 = 0; j2 < 4; ++j2) {
      _Float16 h, l; split2s(QXa4[j2], h, l);
      h4[j2] = h; l4[j2] = l;
    }
    *(v4h*)(RQh + (8+c16)*136 + nb*16 + 4*q) = h4;
    *(v4h*)(RQl + (8+c16)*136 + nb*16 + 4*q) = l4;
  }
  __syncthreads();

  const float Sdt = (float)S * dt;
  #pragma unroll
  for (int cbi = 0; cbi < 4; ++cbi) {
    int cb = nb*4 + cbi;
    v4f aH={0,0,0,0}, aC0={0,0,0,0}, aC1={0,0,0,0};
    #pragma unroll
    for (int kb = 0; kb < 4; ++kb) {
      int bo = ((cb*4 + kb)*64 + lane)*8;
      v8h Bh = *(const v8h*)(wH + bo);
      v8h Bl = *(const v8h*)(wL + bo);
      int ao = c16*136 + kb*32 + q*8;
      v8h Ah = *(const v8h*)(RQh + ao);
      v8h Al = *(const v8h*)(RQl + ao);
      aH = MFMAH(Ah, Bh, aH, 0,0,0);
      if (kb & 1) {
        aC1 = MFMAH(Ah, Bl, aC1, 0,0,0);
        aC1 = MFMAH(Al, Bh, aC1, 0,0,0);
      } else {
        aC0 = MFMAH(Ah, Bl, aC0, 0,0,0);
        aC0 = MFMAH(Al, Bh, aC0, 0,0,0);
      }
    }
    float r0 = (aH[0] + (aC0[0]+aC1[0])*INV2048)*INV256;
    float r1 = (aH[1] + (aC0[1]+aC1[1])*INV2048)*INV256;
    float r2 = (aH[2] + (aC0[2]+aC1[2])*INV2048)*INV256;
    float r3 = (aH[3] + (aC0[3]+aC1[3])*INV2048)*INV256;
    float o0 = __shfl_xor(r0, 32, 64);
    float o1 = __shfl_xor(r1, 32, 64);
    float o2 = __shfl_xor(r2, 32, 64);
    float o3 = __shfl_xor(r3, 32, 64);
    if (q < 2) {
      float abv[4] = {r0, r1, r2, r3};
      float axv[4] = {o0, o1, o2, o3};
      #pragma unroll
      for (int i4 = 0; i4 < 4; ++i4) {
        int off = (rb + 4*q + i4)*512 + cb*16 + c16;
        float x0 = xg[off], v0 = vg[off], f0 = fg[off];
        outg[off]           = x0 + Sdt*v0 + 0.5f*Sdt*Sdt*f0 - dt*dt*axv[i4];
        outg[2097152 + off] = v0 + Sdt*f0 - dt*abv[i4];
      }
    }
  }
}

extern "C" void kernel_launch(void* const* d_in, const int* in_sizes, int n_in,
                              void* d_out, int out_size, void* d_ws, size_t ws_size,
                              hipStream_t stream) {
  const float* x = (const float*)d_in[0];
  const float* v = (const float*)d_in[1];
  const float* f = (const float*)d_in[2];
  const float* U = (const float*)d_in[3];
  const float* W = (const float*)d_in[4];
  _Float16* ws = (_Float16*)d_ws;

  k_prep1<<<dim3(512), dim3(256), 0, stream>>>(U, W, ws);
  k_prep2<<<dim3(8),   dim3(512), 0, stream>>>(W, ws);
  dp5_main<<<dim3(512), dim3(512), 0, stream>>>(
      x, v, f, d_in[5], ws, (float*)d_out);
}

// Round 13
// 149.725 us; speedup vs baseline: 1.1226x; 1.1226x over previous
//
#include <hip/hip_runtime.h>

// DP5 integrator, MI355X. fp32 in/out. Rank-128 recursion vs G'=-256·(W@U).
// R13: transposed stage GEMM (R12-validated numerics) + balanced phase1:
// row-partner state — lane(q,c16) owns (batch row c16&7, ss cols 4q+{0,1} or
// 4q+{2,3} by c16 half). All 64 lanes compute 2 P cols (R11 chain length).
// Packed B-tile (Ph rows 0-7 | Pl rows 8-15), stride 144 (16B-aligned, 4-way
// banks vs 8-way at 136). 8 MFMA + 6 shfl/stage, one barrier, dbuf.
// Projections R11-verbatim; bounce re-indexed; epilogue/prep R11-verbatim.

typedef _Float16 v8h __attribute__((ext_vector_type(8)));
typedef float v4f __attribute__((ext_vector_type(4)));
typedef unsigned short u16;
typedef unsigned int u32;

#define MFMAH __builtin_amdgcn_mfma_f32_16x16x32_f16
#define INV2048 4.8828125e-4f
#define INV256  0.00390625f
#define SSTR 144   // stage tile row stride (halfs)

struct Tab {
  double a[7][7]; double b[7]; double A[7]; double XC[7][7]; double XF[7]; double cxc[7];
};
static constexpr Tab make_tab() {
  Tab t{};
  t.a[2][1]=1.0/5;
  t.a[3][1]=3.0/40;       t.a[3][2]=9.0/40;
  t.a[4][1]=44.0/45;      t.a[4][2]=-56.0/15;      t.a[4][3]=32.0/9;
  t.a[5][1]=19372.0/6561; t.a[5][2]=-25360.0/2187; t.a[5][3]=64448.0/6561; t.a[5][4]=-212.0/729;
  t.a[6][1]=9017.0/3168;  t.a[6][2]=-355.0/33;     t.a[6][3]=46732.0/5247; t.a[6][4]=49.0/176; t.a[6][5]=-5103.0/18656;
  t.b[1]=35.0/384; t.b[2]=0.0; t.b[3]=500.0/1113; t.b[4]=125.0/192; t.b[5]=-2187.0/6784; t.b[6]=11.0/84;
  for (int i=1;i<=6;++i){ double s=0; for(int j=1;j<i;++j) s+=t.a[i][j]; t.A[i]=s; }
  for (int i=1;i<=6;++i) for(int l=1;l<i;++l){ double s=0; for(int j=l+1;j<i;++j) s+=t.a[i][j]*t.a[j][l]; t.XC[i][l]=s; }
  for (int i=1;i<=6;++i){ double s=0; for(int j=1;j<i;++j) s+=t.a[i][j]*t.A[j]; t.XF[i]=s; }
  for (int j=1;j<=6;++j){ double s=0; for (int i=j+1;i<=6;++i) s+=t.b[i]*t.a[i][j]; t.cxc[j]=s; }
  return t;
}
static constexpr Tab TB = make_tab();

__device__ __forceinline__ int decode_steps(const void* p){
  int v = *(const int*)p;
  if (v >= 1 && v <= 512) return v;
  float f = *(const float*)p;
  if (f >= 1.f && f <= 512.f) return (int)f;
  return 8;
}
__device__ __forceinline__ void split2s(float x, _Float16& h, _Float16& l){
  h = (_Float16)x;
  l = (_Float16)((x - (float)h) * 2048.0f);
}

#define WS_GH 0
#define WS_GL 16384
#define WS_UH 32768
#define WS_UL 98304
#define WS_WH 163840
#define WS_WL 229376

__global__ __launch_bounds__(256) void k_prep1(const float* __restrict__ U,
                                               const float* __restrict__ W,
                                               _Float16* __restrict__ ws){
  const int b = blockIdx.x, tid = threadIdx.x;
  if (b < 256) {
    int idx = b*256 + tid;
    int r = idx >> 7, c = idx & 127;
    _Float16 h, l; split2s(U[idx]*256.f, h, l);
    int kb=r>>5, q=(r>>3)&3, j=r&7, nb=c>>4, cl=c&15;
    int slot = ((nb*16+kb)*64 + q*16+cl)*8 + j;
    ws[WS_UH + slot] = h; ws[WS_UL + slot] = l;
  } else {
    int idx = (b-256)*256 + tid;
    int r = idx >> 9, c = idx & 511;
    _Float16 h, l; split2s(W[idx]*256.f, h, l);
    int kb=r>>5, q=(r>>3)&3, j=r&7, nb=c>>4, cl=c&15;
    int slot = ((nb*4+kb)*64 + q*16+cl)*8 + j;
    ws[WS_WH + slot] = h; ws[WS_WL + slot] = l;
  }
}

__global__ __launch_bounds__(512) void k_prep2(const float* __restrict__ W,
                                               _Float16* __restrict__ ws){
  const int tid = threadIdx.x, b = blockIdx.x;
  const int ww = tid >> 6, lane = tid & 63, q = lane >> 4, c16 = lane & 15;
  const int nb = ww;
  const _Float16* uH = ws + WS_UH;
  const _Float16* uL = ws + WS_UL;
  v4f aH = {0,0,0,0}, aC0 = {0,0,0,0}, aC1 = {0,0,0,0};
  #pragma unroll
  for (int kb = 0; kb < 16; ++kb) {
    const float* wp = W + (b*16 + c16)*512 + kb*32 + q*8;
    float4 w0 = *(const float4*)wp;
    float4 w1 = *(const float4*)(wp + 4);
    float wv[8] = {w0.x,w0.y,w0.z,w0.w, w1.x,w1.y,w1.z,w1.w};
    v8h Ah, Al;
    #pragma unroll
    for (int j = 0; j < 8; ++j) {
      _Float16 h, l; split2s(-wv[j], h, l);
      Ah[j] = h; Al[j] = l;
    }
    int bo = ((nb*16 + kb)*64 + lane)*8;
    v8h Bh = *(const v8h*)(uH + bo);
    v8h Bl = *(const v8h*)(uL + bo);
    aH = MFMAH(Ah, Bh, aH, 0,0,0);
    if (kb & 1) {
      aC1 = MFMAH(Ah, Bl, aC1, 0,0,0);
      aC1 = MFMAH(Al, Bh, aC1, 0,0,0);
    } else {
      aC0 = MFMAH(Ah, Bl, aC0, 0,0,0);
      aC0 = MFMAH(Al, Bh, aC0, 0,0,0);
    }
  }
  #pragma unroll
  for (int r = 0; r < 4; ++r) {
    float g = aH[r] + (aC0[r] + aC1[r])*INV2048;
    _Float16 h, l; split2s(g, h, l);
    int m = b*16 + 4*q + r, n = nb*16 + c16;
    int slot = (((n>>4)*4 + (m>>5))*64 + ((m>>3)&3)*16 + (n&15))*8 + (m&7);
    ws[WS_GH + slot] = h; ws[WS_GL + slot] = l;
  }
}

#define ARENA 33280

__global__ __launch_bounds__(512,4) void dp5_main(
    const float* __restrict__ xg, const float* __restrict__ vg,
    const float* __restrict__ fg, const void* stepsp,
    const _Float16* __restrict__ ws, float* __restrict__ outg)
{
  __shared__ __align__(16) char arena[ARENA];
  _Float16* base = (_Float16*)arena;
  const _Float16* uH = ws + WS_UH;
  const _Float16* uL = ws + WS_UL;
  const _Float16* wH = ws + WS_WH;
  const _Float16* wL = ws + WS_WL;

  const int tid  = threadIdx.x;
  const int ww   = tid >> 6;
  const int lane = tid & 63;
  const int q    = lane >> 4;
  const int c16  = lane & 15;
  const int nb   = ww;
  const int kcol = nb*16 + c16;
  const int srcl = (q>>1)*16 + c16;
  const bool odd = (q & 1);
  const int rb   = blockIdx.x * 8;
  const int S    = decode_steps(stepsp);
  const float dt = 0.01f;
  // row-partner ownership
  const int  brow = c16 & 7;
  const bool hiC  = (c16 >= 8);
  const int  kc0  = nb*16 + 4*q + (hiC ? 2 : 0);   // owns cols kc0, kc0+1

  v8h Gh[4], Gl[4];
  #pragma unroll
  for (int kb = 0; kb < 4; ++kb) {
    int off = ((nb*4 + kb)*64 + lane)*8;
    Gh[kb] = *(const v8h*)(ws + WS_GH + off);
    Gl[kb] = *(const v8h*)(ws + WS_GL + off);
  }

  // ---- projections (R11-verbatim) -> spread xU0/vU0/fU0 ----
  _Float16* tH = base;
  _Float16* tL = base + 8320;
  const int r16 = tid >> 5, c0 = (tid & 31)*16;
  float xU0[2], vU0[2], fU0[2];
  for (int pass = 0; pass < 2; ++pass) {
    if (pass == 0 || r16 < 8) {
      const float* sp;
      if (pass == 0) sp = (r16 < 8) ? (xg + (rb + r16)*512) : (vg + (rb + r16 - 8)*512);
      else           sp = fg + (rb + r16)*512;
      sp += c0;
      float4 g0 = *(const float4*)(sp);
      float4 g1 = *(const float4*)(sp + 4);
      float4 g2 = *(const float4*)(sp + 8);
      float4 g3 = *(const float4*)(sp + 12);
      float vals[16] = {g0.x,g0.y,g0.z,g0.w, g1.x,g1.y,g1.z,g1.w,
                        g2.x,g2.y,g2.z,g2.w, g3.x,g3.y,g3.z,g3.w};
      v8h vh0, vh1, vl0, vl1;
      #pragma unroll
      for (int j = 0; j < 8; ++j) {
        _Float16 h, l;
        split2s(vals[j], h, l);     vh0[j] = h; vl0[j] = l;
        split2s(vals[8+j], h, l);   vh1[j] = h; vl1[j] = l;
      }
      int o = r16*520 + c0;
      *(v8h*)(tH + o) = vh0; *(v8h*)(tH + o + 8) = vh1;
      *(v8h*)(tL + o) = vl0; *(v8h*)(tL + o + 8) = vl1;
    }
    __syncthreads();
    v4f aH0={0,0,0,0}, aH1={0,0,0,0}, aC0={0,0,0,0}, aC1={0,0,0,0};
    #pragma unroll
    for (int kb = 0; kb < 16; ++kb) {
      int ao = c16*520 + kb*32 + q*8;
      v8h Ah = *(const v8h*)(tH + ao);
      v8h Al = *(const v8h*)(tL + ao);
      int bo = ((nb*16 + kb)*64 + lane)*8;
      v8h Bh = *(const v8h*)(uH + bo);
      v8h Bl = *(const v8h*)(uL + bo);
      if (kb & 1) {
        aH1 = MFMAH(Ah, Bh, aH1, 0,0,0);
        aC1 = MFMAH(Ah, Bl, aC1, 0,0,0);
        aC1 = MFMAH(Al, Bh, aC1, 0,0,0);
      } else {
        aH0 = MFMAH(Ah, Bh, aH0, 0,0,0);
        aC0 = MFMAH(Ah, Bl, aC0, 0,0,0);
        aC0 = MFMAH(Al, Bh, aC0, 0,0,0);
      }
    }
    float at0 = ((aH0[0]+aH1[0]) + (aC0[0]+aC1[0])*INV2048)*INV256;
    float at1 = ((aH0[1]+aH1[1]) + (aC0[1]+aC1[1])*INV2048)*INV256;
    float at2 = ((aH0[2]+aH1[2]) + (aC0[2]+aC1[2])*INV2048)*INV256;
    float at3 = ((aH0[3]+aH1[3]) + (aC0[3]+aC1[3])*INV2048)*INV256;
    if (pass == 0) {
      float sx0=__shfl(at0,srcl,64), sx1=__shfl(at1,srcl,64);
      float sx2=__shfl(at2,srcl,64), sx3=__shfl(at3,srcl,64);
      xU0[0] = odd ? sx2 : sx0; xU0[1] = odd ? sx3 : sx1;
      int srclv = srcl + 32;
      float sv0=__shfl(at0,srclv,64), sv1=__shfl(at1,srclv,64);
      float sv2=__shfl(at2,srclv,64), sv3=__shfl(at3,srclv,64);
      vU0[0] = odd ? sv2 : sv0; vU0[1] = odd ? sv3 : sv1;
    } else {
      float sf0=__shfl(at0,srcl,64), sf1=__shfl(at1,srcl,64);
      float sf2=__shfl(at2,srcl,64), sf3=__shfl(at3,srcl,64);
      fU0[0] = odd ? sf2 : sf0; fU0[1] = odd ? sf3 : sf1;
    }
    __syncthreads();
  }

  // ---- bounce spread -> row-partner state (float2 per lane) ----
  float cxU2[2], cvU2[2], fU2[2];
  {
    float* T = (float*)arena;
    #pragma unroll
    for (int p2 = 0; p2 < 3; ++p2) {
      float i0 = (p2==0) ? xU0[0] : (p2==1) ? vU0[0] : fU0[0];
      float i1 = (p2==0) ? xU0[1] : (p2==1) ? vU0[1] : fU0[1];
      T[(2*q + 0)*132 + kcol] = i0;
      T[(2*q + 1)*132 + kcol] = i1;
      __syncthreads();
      float2 t2 = *(const float2*)(T + brow*132 + kc0);
      float* o = (p2==0) ? cxU2 : (p2==1) ? cvU2 : fU2;
      o[0] = t2.x; o[1] = t2.y;
      __syncthreads();
    }
  }

  // ---- rank-128 recursion: transposed GEMM, balanced phase1 ----
  float kU6[6][2], Rr2[2], QXa2[2];
  #pragma unroll
  for (int j = 0; j < 2; ++j) {
    Rr2[j] = 0.f; QXa2[j] = 0.f;
    #pragma unroll
    for (int l = 0; l < 6; ++l) kU6[l][j] = 0.f;
  }

  int pb = 0;
  for (int s = 0; s < S; ++s) {
    float accX[2], accV[2], Pbs[2], Pxcs[2];
    #pragma unroll
    for (int j = 0; j < 2; ++j) { accX[j]=0.f; accV[j]=0.f; Pbs[j]=0.f; Pxcs[j]=0.f; }

    #pragma unroll
    for (int i = 1; i <= 6; ++i) {
      _Float16* bT = base + (pb ? 2304 : 0);
      const float dtA   = dt*(float)TB.A[i];
      const float dt2XF = dt*dt*(float)TB.XF[i];
      const float bi    = (float)TB.b[i];
      const float ci    = (float)TB.cxc[i];
      // phase1: all lanes, 2 cols each (row brow, cols kc0..kc0+1)
      {
        union { _Float16 h[2]; u32 u; } ph, pl;
        #pragma unroll
        for (int j2 = 0; j2 < 2; ++j2) {
          float vv = cvU2[j2] + dtA*fU2[j2];
          float xx = cxU2[j2] + dtA*cvU2[j2] + dt2XF*fU2[j2];
          #pragma unroll
          for (int l = 1; l < i; ++l) {
            vv += (dt*(float)TB.a[i][l]) * kU6[l-1][j2];
            xx += (dt*dt*(float)TB.XC[i][l]) * kU6[l-1][j2];
          }
          float p = vv*xx;
          Pbs[j2] += bi*p; Pxcs[j2] += ci*p;
          _Float16 h, l2; split2s(p, h, l2);
          ph.h[j2] = h; pl.h[j2] = l2;
        }
        *(u32*)(bT + brow*SSTR + kc0)       = ph.u;   // Ph rows 0-7
        *(u32*)(bT + (8+brow)*SSTR + kc0)   = pl.u;   // Pl rows 8-15
      }
      __syncthreads();
      // transposed MFMA: A = G frags, B = packed P-tile
      v4f C1 = {0,0,0,0}, C2 = {0,0,0,0};
      #pragma unroll
      for (int kb = 0; kb < 4; ++kb) {
        v8h B = *(const v8h*)(bT + c16*SSTR + kb*32 + q*8);
        C1 = MFMAH(Gh[kb], B, C1, 0,0,0);
        C2 = MFMAH(Gl[kb], B, C2, 0,0,0);
      }
      // combine (valid on c16<8), distribute regs 2,3 to partners
      float kv[4];
      #pragma unroll
      for (int r = 0; r < 4; ++r) {
        float oth = __shfl_xor(C1[r], 8, 64);
        kv[r] = (C1[r] + (oth + C2[r])*INV2048)*INV256;
      }
      float k2 = __shfl_xor(kv[2], 8, 64);
      float k3 = __shfl_xor(kv[3], 8, 64);
      float kva = hiC ? k2 : kv[0];
      float kvb = hiC ? k3 : kv[1];
      kU6[i-1][0] = kva; kU6[i-1][1] = kvb;
      accX[0] += ci*kva; accV[0] += bi*kva;
      accX[1] += ci*kvb; accV[1] += bi*kvb;
      pb ^= 1;
    }

    #pragma unroll
    for (int j = 0; j < 2; ++j) {
      float nx = cxU2[j] + dt*cvU2[j] + dt*dt*(accX[j] + 0.5f*fU2[j]);
      cvU2[j] += dt*(accV[j] + fU2[j]);
      cxU2[j]  = nx;
      QXa2[j] += Rr2[j] + Pxcs[j];
      Rr2[j]  += Pbs[j];
    }
  }

  // ---- epilogue: fill R|QX tiles (rows 0-7 = R, 8-15 = QX; h/l), R11 MFMA loop
  __syncthreads();
  _Float16* RQh = base;
  _Float16* RQl = base + 2176;
  {
    union { _Float16 h[2]; u32 u; } t1, t2, t3, t4;
    #pragma unroll
    for (int j2 = 0; j2 < 2; ++j2) {
      _Float16 h, l;
      split2s(Rr2[j2], h, l);  t1.h[j2] = h; t2.h[j2] = l;
      split2s(QXa2[j2], h, l); t3.h[j2] = h; t4.h[j2] = l;
    }
    *(u32*)(RQh + brow*136 + kc0)     = t1.u;
    *(u32*)(RQl + brow*136 + kc0)     = t2.u;
    *(u32*)(RQh + (8+brow)*136 + kc0) = t3.u;
    *(u32*)(RQl + (8+brow)*136 + kc0) = t4.u;
  }
  __syncthreads();

  const float Sdt = (float)S * dt;
  #pragma unroll
  for (int cbi = 0; cbi < 4; ++cbi) {
    int cb = nb*4 + cbi;
    v4f aH={0,0,0,0}, aC0={0,0,0,0}, aC1={0,0,0,0};
    #pragma unroll
    for (int kb = 0; kb < 4; ++kb) {
      int bo = ((cb*4 + kb)*64 + lane)*8;
      v8h Bh = *(const v8h*)(wH + bo);
      v8h Bl = *(const v8h*)(wL + bo);
      int ao = c16*136 + kb*32 + q*8;
      v8h Ah = *(const v8h*)(RQh + ao);
      v8h Al = *(const v8h*)(RQl + ao);
      aH = MFMAH(Ah, Bh, aH, 0,0,0);
      if (kb & 1) {
        aC1 = MFMAH(Ah, Bl, aC1, 0,0,0);
        aC1 = MFMAH(Al, Bh, aC1, 0,0,0);
      } else {
        aC0 = MFMAH(Ah, Bl, aC0, 0,0,0);
        aC0 = MFMAH(Al, Bh, aC0, 0,0,0);
      }
    }
    float r0 = (aH[0] + (aC0[0]+aC1[0])*INV2048)*INV256;
    float r1 = (aH[1] + (aC0[1]+aC1[1])*INV2048)*INV256;
    float r2 = (aH[2] + (aC0[2]+aC1[2])*INV2048)*INV256;
    float r3 = (aH[3] + (aC0[3]+aC1[3])*INV2048)*INV256;
    float o0 = __shfl_xor(r0, 32, 64);
    float o1 = __shfl_xor(r1, 32, 64);
    float o2 = __shfl_xor(r2, 32, 64);
    float o3 = __shfl_xor(r3, 32, 64);
    if (q < 2) {
      float abv[4] = {r0, r1, r2, r3};
      float axv[4] = {o0, o1, o2, o3};
      #pragma unroll
      for (int i4 = 0; i4 < 4; ++i4) {
        int off = (rb + 4*q + i4)*512 + cb*16 + c16;
        float x0 = xg[off], v0 = vg[off], f0 = fg[off];
        outg[off]           = x0 + Sdt*v0 + 0.5f*Sdt*Sdt*f0 - dt*dt*axv[i4];
        outg[2097152 + off] = v0 + Sdt*f0 - dt*abv[i4];
      }
    }
  }
}

extern "C" void kernel_launch(void* const* d_in, const int* in_sizes, int n_in,
                              void* d_out, int out_size, void* d_ws, size_t ws_size,
                              hipStream_t stream) {
  const float* x = (const float*)d_in[0];
  const float* v = (const float*)d_in[1];
  const float* f = (const float*)d_in[2];
  const float* U = (const float*)d_in[3];
  const float* W = (const float*)d_in[4];
  _Float16* ws = (_Float16*)d_ws;

  k_prep1<<<dim3(512), dim3(256), 0, stream>>>(U, W, ws);
  k_prep2<<<dim3(8),   dim3(512), 0, stream>>>(W, ws);
  dp5_main<<<dim3(512), dim3(512), 0, stream>>>(
      x, v, f, d_in[5], ws, (float*)d_out);
}